// Round 9
// baseline (71.924 us; speedup 1.0000x reference)
//
#include <hip/hip_runtime.h>
#include <hip/hip_cooperative_groups.h>
#include <math.h>

#define DT 0.005f
#define NTHREADS 256
#define COOP_BLOCKS 2048
#define NBLOCKS 2048

namespace cg = cooperative_groups;

typedef float fvec4 __attribute__((ext_vector_type(4)));

__device__ __forceinline__ fvec4 ntload4f(const float* p) {
    return __builtin_nontemporal_load(reinterpret_cast<const fvec4*>(p));
}
__device__ __forceinline__ float ntloadf(const float* p) {
    return __builtin_nontemporal_load(p);
}
__device__ __forceinline__ int ntloadi(const int* p) {
    return __builtin_nontemporal_load(p);
}

__device__ __forceinline__ void stream_compute(
    const float* __restrict__ quat, const float* __restrict__ tpos,
    const float* __restrict__ bias, const float* __restrict__ batchX,
    int i, int SF, int last_off,
    float gx, float gy, float gz, float half_dt2,
    float& cx, float& cy, float& cz)
{
    fvec4 q = ntload4f(quat + (size_t)i * 4);
    const float* tp = tpos + (size_t)i * 3;
    float tpx = ntloadf(tp + 0), tpy = ntloadf(tp + 1), tpz = ntloadf(tp + 2);
    const float* bp = bias + (size_t)i * 3;
    float bx = ntloadf(bp + 0), by = ntloadf(bp + 1), bz = ntloadf(bp + 2);
    const float* xb = batchX + (size_t)i * SF + last_off;
    float ax = ntloadf(xb + 0) - bx;
    float ay = ntloadf(xb + 1) - by;
    float az = ntloadf(xb + 2) - bz;

    // quat_rotate(q, a): t = q * (0, a); result = (t * q_conj).vec
    float t0 = -(q.y * ax + q.z * ay + q.w * az);
    float t1 =   q.x * ax + q.z * az - q.w * ay;
    float t2 =   q.x * ay - q.y * az + q.w * ax;
    float t3 =   q.x * az + q.y * ay - q.z * ax;
    float rx = -t0 * q.y + t1 * q.x - t2 * q.w + t3 * q.z;
    float ry = -t0 * q.z + t1 * q.w + t2 * q.x - t3 * q.y;
    float rz = -t0 * q.w - t1 * q.z + t2 * q.y + t3 * q.x;

    cx = half_dt2 * (gx + rx) - tpx;
    cy = half_dt2 * (gy + ry) - tpy;
    cz = half_dt2 * (gz + rz) - tpz;
}

__device__ __forceinline__ float huber3(float dx, float dy, float dz) {
    float adx = fabsf(dx), ady = fabsf(dy), adz = fabsf(dz);
    float h = (adx < 1.f) ? 0.5f * dx * dx : adx - 0.5f;
    h += (ady < 1.f) ? 0.5f * dy * dy : ady - 0.5f;
    h += (adz < 1.f) ? 0.5f * dz * dz : adz - 0.5f;
    return h;
}

// ---------------- Cooperative fused kernel: requires B == 2*grid*block ----------------
__global__ __launch_bounds__(NTHREADS, 8) void pos_loss_coop(
    const float* __restrict__ quat,
    const float* __restrict__ tpos,
    const float* __restrict__ bias,
    const float* __restrict__ batchX,
    const float* __restrict__ pos_all,
    const float* __restrict__ vel_all,
    const float* __restrict__ grav,
    const int*   __restrict__ indices,
    const int*   __restrict__ seq_len_p,
    int B, int SF,
    float* __restrict__ partials,
    float inv_cnt,
    float* __restrict__ out)
{
    cg::grid_group grid = cg::this_grid();

    const int S = *seq_len_p;
    const int F = SF / S;
    const int last_off = (S - 1) * F;
    const float gx = grav[0], gy = grav[1], gz = grav[2];
    const float half_dt2 = 0.5f * DT * DT;

    const int T   = gridDim.x * blockDim.x;        // 524288
    const int tid = blockIdx.x * blockDim.x + threadIdx.x;
    const int i0  = tid;                           // element 0
    const int i1  = tid + T;                       // element 1

    // ---- Phase 1: pure streaming; state kept in registers ----
    int id0 = ntloadi(indices + i0) - (S - 1); if (id0 < 0) id0 = 0;
    int id1 = ntloadi(indices + i1) - (S - 1); if (id1 < 0) id1 = 0;

    float c0x, c0y, c0z, c1x, c1y, c1z;
    stream_compute(quat, tpos, bias, batchX, i0, SF, last_off,
                   gx, gy, gz, half_dt2, c0x, c0y, c0z);
    stream_compute(quat, tpos, bias, batchX, i1, SF, last_off,
                   gx, gy, gz, half_dt2, c1x, c1y, c1z);

    // ---- barrier: all streaming traffic done before any gather issues ----
    grid.sync();

    // ---- Phase 2: pure gathers ----
    const float* pp0 = pos_all + (size_t)id0 * 3;
    const float* vp0 = vel_all + (size_t)id0 * 3;
    const float* pp1 = pos_all + (size_t)id1 * 3;
    const float* vp1 = vel_all + (size_t)id1 * 3;
    float p00 = pp0[0], p01 = pp0[1], p02 = pp0[2];
    float v00 = vp0[0], v01 = vp0[1], v02 = vp0[2];
    float p10 = pp1[0], p11 = pp1[1], p12 = pp1[2];
    float v10 = vp1[0], v11 = vp1[1], v12 = vp1[2];

    float hsum = huber3(p00 + v00 * DT + c0x,
                        p01 + v01 * DT + c0y,
                        p02 + v02 * DT + c0z)
               + huber3(p10 + v10 * DT + c1x,
                        p11 + v11 * DT + c1y,
                        p12 + v12 * DT + c1z);

    // block reduction
    for (int off = 32; off > 0; off >>= 1)
        hsum += __shfl_down(hsum, off);

    __shared__ float wsum[NTHREADS / 64];
    int lane = threadIdx.x & 63;
    int wid  = threadIdx.x >> 6;
    if (lane == 0) wsum[wid] = hsum;
    __syncthreads();

    if (threadIdx.x == 0) {
        float s = 0.f;
        for (int w = 0; w < NTHREADS / 64; ++w) s += wsum[w];
        partials[blockIdx.x] = s;
    }
    __threadfence();

    // ---- Phase 3: final reduction by block 0 ----
    grid.sync();

    if (blockIdx.x == 0) {
        float s = 0.f;
        for (int i = threadIdx.x; i < (int)gridDim.x; i += blockDim.x)
            s += partials[i];
        for (int off = 32; off > 0; off >>= 1)
            s += __shfl_down(s, off);
        __syncthreads();
        if (lane == 0) wsum[wid] = s;
        __syncthreads();
        if (threadIdx.x == 0) {
            float tot = 0.f;
            for (int w = 0; w < NTHREADS / 64; ++w) tot += wsum[w];
            out[0] = tot * inv_cnt;
        }
    }
}

// ---------------- Fallback: proven round-5 single-pass ----------------
__global__ __launch_bounds__(NTHREADS) void pos_loss_partial(
    const float* __restrict__ quat,
    const float* __restrict__ tpos,
    const float* __restrict__ bias,
    const float* __restrict__ batchX,
    const float* __restrict__ pos_all,
    const float* __restrict__ vel_all,
    const float* __restrict__ grav,
    const int*   __restrict__ indices,
    const int*   __restrict__ seq_len_p,
    int B, int SF,
    float* __restrict__ partials)
{
    const int S = *seq_len_p;
    const int F = SF / S;
    const int last_off = (S - 1) * F;
    const float gx = grav[0], gy = grav[1], gz = grav[2];
    const float half_dt2 = 0.5f * DT * DT;

    float hsum = 0.f;

    for (int i = blockIdx.x * blockDim.x + threadIdx.x; i < B;
         i += gridDim.x * blockDim.x) {

        int idx = ntloadi(indices + i) - (S - 1);
        if (idx < 0) idx = 0;
        const float* pp = pos_all + (size_t)idx * 3;
        const float* vp = vel_all + (size_t)idx * 3;
        float p0x = pp[0], p0y = pp[1], p0z = pp[2];
        float v0x = vp[0], v0y = vp[1], v0z = vp[2];

        float cx, cy, cz;
        stream_compute(quat, tpos, bias, batchX, i, SF, last_off,
                       gx, gy, gz, half_dt2, cx, cy, cz);

        hsum += huber3(p0x + v0x * DT + cx,
                       p0y + v0y * DT + cy,
                       p0z + v0z * DT + cz);
    }

    for (int off = 32; off > 0; off >>= 1)
        hsum += __shfl_down(hsum, off);

    __shared__ float wsum[NTHREADS / 64];
    int lane = threadIdx.x & 63;
    int wid  = threadIdx.x >> 6;
    if (lane == 0) wsum[wid] = hsum;
    __syncthreads();

    if (threadIdx.x == 0) {
        float s = 0.f;
        for (int w = 0; w < NTHREADS / 64; ++w) s += wsum[w];
        partials[blockIdx.x] = s;
    }
}

__global__ __launch_bounds__(NTHREADS) void pos_loss_finish(
    const float* __restrict__ partials, int nb, float inv_cnt,
    float* __restrict__ out)
{
    float s = 0.f;
    for (int i = threadIdx.x; i < nb; i += NTHREADS) s += partials[i];

    for (int off = 32; off > 0; off >>= 1)
        s += __shfl_down(s, off);

    __shared__ float wsum[NTHREADS / 64];
    int lane = threadIdx.x & 63;
    int wid  = threadIdx.x >> 6;
    if (lane == 0) wsum[wid] = s;
    __syncthreads();

    if (threadIdx.x == 0) {
        float tot = 0.f;
        for (int w = 0; w < NTHREADS / 64; ++w) tot += wsum[w];
        out[0] = tot * inv_cnt;
    }
}

extern "C" void kernel_launch(void* const* d_in, const int* in_sizes, int n_in,
                              void* d_out, int out_size, void* d_ws, size_t ws_size,
                              hipStream_t stream) {
    const float* quat    = (const float*)d_in[0];
    const float* tpos    = (const float*)d_in[1];
    const float* bias    = (const float*)d_in[2];
    const float* batchX  = (const float*)d_in[3];
    const float* pos_all = (const float*)d_in[4];
    const float* vel_all = (const float*)d_in[5];
    const float* grav    = (const float*)d_in[6];
    const int*   indices = (const int*)d_in[7];
    const int*   seqlen  = (const int*)d_in[8];

    int B  = in_sizes[0] / 4;
    int SF = in_sizes[3] / B;

    float* partials = (float*)d_ws;
    float* outp     = (float*)d_out;
    float inv_cnt = (float)(1.0 / (3.0 * (double)B));

    // ---- decide if the cooperative fused kernel is usable (capture-safe queries) ----
    bool coop_ok = (B == 2 * COOP_BLOCKS * NTHREADS) &&
                   (ws_size >= COOP_BLOCKS * sizeof(float));
    if (coop_ok) {
        int dev = 0;
        hipGetDevice(&dev);
        int coop_attr = 0;
        hipDeviceGetAttribute(&coop_attr, hipDeviceAttributeCooperativeLaunch, dev);
        int num_cu = 0;
        hipDeviceGetAttribute(&num_cu, hipDeviceAttributeMultiprocessorCount, dev);
        int max_blk = 0;
        hipOccupancyMaxActiveBlocksPerMultiprocessor(&max_blk, pos_loss_coop,
                                                     NTHREADS, 0);
        coop_ok = coop_attr && (max_blk * num_cu >= COOP_BLOCKS);
    }

    if (coop_ok) {
        void* args[] = {
            (void*)&quat, (void*)&tpos, (void*)&bias, (void*)&batchX,
            (void*)&pos_all, (void*)&vel_all, (void*)&grav, (void*)&indices,
            (void*)&seqlen, (void*)&B, (void*)&SF, (void*)&partials,
            (void*)&inv_cnt, (void*)&outp
        };
        hipError_t err = hipLaunchCooperativeKernel(
            (const void*)pos_loss_coop, dim3(COOP_BLOCKS), dim3(NTHREADS),
            args, 0, stream);
        if (err == hipSuccess) return;
        // fall through to fallback on failure (nothing was enqueued)
    }

    pos_loss_partial<<<NBLOCKS, NTHREADS, 0, stream>>>(
        quat, tpos, bias, batchX, pos_all, vel_all, grav, indices, seqlen,
        B, SF, partials);
    pos_loss_finish<<<1, NTHREADS, 0, stream>>>(
        partials, NBLOCKS, inv_cnt, outp);
}

// Round 10
// 63.301 us; speedup vs baseline: 1.1362x; 1.1362x over previous
//
#include <hip/hip_runtime.h>
#include <math.h>

#define DT 0.005f
#define NTHREADS 256
#define NBLOCKS 2048
#define NBUCKET 16

typedef float fvec4 __attribute__((ext_vector_type(4)));

__device__ __forceinline__ fvec4 ntload4f(const float* p) {
    return __builtin_nontemporal_load(reinterpret_cast<const fvec4*>(p));
}
__device__ __forceinline__ float ntloadf(const float* p) {
    return __builtin_nontemporal_load(p);
}
__device__ __forceinline__ int ntloadi(const int* p) {
    return __builtin_nontemporal_load(p);
}

__device__ __forceinline__ void stream_compute(
    const float* __restrict__ quat, const float* __restrict__ tpos,
    const float* __restrict__ bias, const float* __restrict__ batchX,
    int i, int SF, int last_off,
    float gx, float gy, float gz, float half_dt2,
    float& cx, float& cy, float& cz)
{
    fvec4 q = ntload4f(quat + (size_t)i * 4);
    const float* tp = tpos + (size_t)i * 3;
    float tpx = ntloadf(tp + 0), tpy = ntloadf(tp + 1), tpz = ntloadf(tp + 2);
    const float* bp = bias + (size_t)i * 3;
    float bx = ntloadf(bp + 0), by = ntloadf(bp + 1), bz = ntloadf(bp + 2);
    const float* xb = batchX + (size_t)i * SF + last_off;
    float ax = ntloadf(xb + 0) - bx;
    float ay = ntloadf(xb + 1) - by;
    float az = ntloadf(xb + 2) - bz;

    float t0 = -(q.y * ax + q.z * ay + q.w * az);
    float t1 =   q.x * ax + q.z * az - q.w * ay;
    float t2 =   q.x * ay - q.y * az + q.w * ax;
    float t3 =   q.x * az + q.y * ay - q.z * ax;
    float rx = -t0 * q.y + t1 * q.x - t2 * q.w + t3 * q.z;
    float ry = -t0 * q.z + t1 * q.w + t2 * q.x - t3 * q.y;
    float rz = -t0 * q.w - t1 * q.z + t2 * q.y + t3 * q.x;

    cx = half_dt2 * (gx + rx) - tpx;
    cy = half_dt2 * (gy + ry) - tpy;
    cz = half_dt2 * (gz + rz) - tpz;
}

__device__ __forceinline__ float huber3(float dx, float dy, float dz) {
    float adx = fabsf(dx), ady = fabsf(dy), adz = fabsf(dz);
    float h = (adx < 1.f) ? 0.5f * dx * dx : adx - 0.5f;
    h += (ady < 1.f) ? 0.5f * dy * dy : ady - 0.5f;
    h += (adz < 1.f) ? 0.5f * dz * dz : adz - 0.5f;
    return h;
}

// ---------------- K1: stream + deterministic 16-bucket multisplit ----------------
// Block owns 512 elements [blockIdx*512, +512). Round 0: e = base+tid, round 1: e = base+256+tid.
__global__ __launch_bounds__(NTHREADS) void k1_bin(
    const float* __restrict__ quat,
    const float* __restrict__ tpos,
    const float* __restrict__ bias,
    const float* __restrict__ batchX,
    const int*   __restrict__ indices,
    const int*   __restrict__ seq_len_p,
    int SF, int shift,
    uint4* __restrict__ pairs,      // B entries, block-contiguous bucket-sorted
    int*   __restrict__ dirs)       // nblocks*16 counts
{
    const int S = *seq_len_p;
    const int F = SF / S;
    const int last_off = (S - 1) * F;
    const float half_dt2 = 0.5f * DT * DT;
    // gravity is tiny; constant folded via grav pointer avoided: passed below
    // (grav loaded in caller-provided args through stream_compute's g terms)

    __shared__ int   cnt[2][4][NBUCKET];      // [round][wave][bucket]
    __shared__ int   offarr[2][4][NBUCKET];
    __shared__ int   bstart[NBUCKET];
    __shared__ uint4 stage[512];

    const int tid  = threadIdx.x;
    const int wave = tid >> 6;
    const int lane = tid & 63;
    const unsigned long long ltmask = (lane == 63) ? ~0ull >> 1 : (1ull << lane) - 1ull;

    if (tid < 2 * 4 * NBUCKET) ((int*)cnt)[tid] = 0;
    __syncthreads();

    const int base = blockIdx.x * 512;

    int   idxv[2], bckt[2], rnk[2];
    float cxv[2], cyv[2], czv[2];

    #pragma unroll
    for (int r = 0; r < 2; ++r) {
        const int i = base + r * 256 + tid;
        int idx = ntloadi(indices + i) - (S - 1);
        if (idx < 0) idx = 0;
        idxv[r] = idx;
        int b = idx >> shift; if (b > NBUCKET - 1) b = NBUCKET - 1;
        bckt[r] = b;

        unsigned long long mask = ~0ull;
        #pragma unroll
        for (int k = 0; k < 4; ++k) {
            unsigned long long bm = __ballot((b >> k) & 1);
            mask &= ((b >> k) & 1) ? bm : ~bm;
        }
        rnk[r] = __popcll(mask & ltmask);
        if (rnk[r] == 0) cnt[r][wave][b] = __popcll(mask);
    }
    __syncthreads();

    // deterministic scan: per bucket over (round, wave) in fixed order
    if (tid < NBUCKET) {
        int b = tid, off = 0;
        #pragma unroll
        for (int r = 0; r < 2; ++r)
            #pragma unroll
            for (int w = 0; w < 4; ++w) {
                offarr[r][w][b] = off;
                off += cnt[r][w][b];
            }
        dirs[blockIdx.x * NBUCKET + b] = off;   // per-block bucket count
        cnt[0][0][b] = off;                      // reuse as totals
    }
    __syncthreads();
    if (tid == 0) {
        int s = 0;
        #pragma unroll
        for (int b = 0; b < NBUCKET; ++b) { bstart[b] = s; s += cnt[0][0][b]; }
    }

    // compute c while scan settles (independent of LDS)
    // note: gravity handled by caller passing grav through constant args below
    __syncthreads();

    // placeholder to keep structure; real c computed in second pass below
    // (stream_compute needs grav; re-declared in wrapper kernel)
    (void)cxv; (void)cyv; (void)czv;

    // This kernel variant is completed by k1_bin_full below.
}

// Full K1 including gravity args (the one actually launched).
__global__ __launch_bounds__(NTHREADS) void k1_bin_full(
    const float* __restrict__ quat,
    const float* __restrict__ tpos,
    const float* __restrict__ bias,
    const float* __restrict__ batchX,
    const float* __restrict__ grav,
    const int*   __restrict__ indices,
    const int*   __restrict__ seq_len_p,
    int SF, int shift,
    uint4* __restrict__ pairs,
    int*   __restrict__ dirs)
{
    const int S = *seq_len_p;
    const int F = SF / S;
    const int last_off = (S - 1) * F;
    const float gx = grav[0], gy = grav[1], gz = grav[2];
    const float half_dt2 = 0.5f * DT * DT;

    __shared__ int   cnt[2][4][NBUCKET];
    __shared__ int   offarr[2][4][NBUCKET];
    __shared__ int   bstart[NBUCKET];
    __shared__ uint4 stage[512];

    const int tid  = threadIdx.x;
    const int wave = tid >> 6;
    const int lane = tid & 63;
    const unsigned long long ltmask = (1ull << lane) - 1ull;  // lane<64; 1ull<<63 ok

    if (tid < 2 * 4 * NBUCKET) ((int*)cnt)[tid] = 0;
    __syncthreads();

    const int base = blockIdx.x * 512;

    int   idxv[2], bckt[2], rnk[2];
    float cxv[2], cyv[2], czv[2];

    #pragma unroll
    for (int r = 0; r < 2; ++r) {
        const int i = base + r * 256 + tid;
        int idx = ntloadi(indices + i) - (S - 1);
        if (idx < 0) idx = 0;
        idxv[r] = idx;
        int b = idx >> shift; if (b > NBUCKET - 1) b = NBUCKET - 1;
        bckt[r] = b;

        unsigned long long mask = ~0ull;
        #pragma unroll
        for (int k = 0; k < 4; ++k) {
            unsigned long long bm = __ballot((b >> k) & 1);
            mask &= ((b >> k) & 1) ? bm : ~bm;
        }
        rnk[r] = __popcll(mask & ltmask);
        if (rnk[r] == 0) cnt[r][wave][b] = __popcll(mask);

        stream_compute(quat, tpos, bias, batchX, i, SF, last_off,
                       gx, gy, gz, half_dt2, cxv[r], cyv[r], czv[r]);
    }
    __syncthreads();

    if (tid < NBUCKET) {
        int b = tid, off = 0;
        #pragma unroll
        for (int r = 0; r < 2; ++r)
            #pragma unroll
            for (int w = 0; w < 4; ++w) {
                offarr[r][w][b] = off;
                off += cnt[r][w][b];
            }
        dirs[blockIdx.x * NBUCKET + b] = off;
        cnt[0][0][b] = off;   // totals (cnt no longer needed raw after offarr built)
    }
    __syncthreads();
    if (tid == 0) {
        int s = 0;
        #pragma unroll
        for (int b = 0; b < NBUCKET; ++b) { bstart[b] = s; s += cnt[0][0][b]; }
    }
    __syncthreads();

    #pragma unroll
    for (int r = 0; r < 2; ++r) {
        int slot = bstart[bckt[r]] + offarr[r][wave][bckt[r]] + rnk[r];
        uint4 v;
        v.x = (unsigned)idxv[r];
        v.y = __float_as_uint(cxv[r]);
        v.z = __float_as_uint(cyv[r]);
        v.w = __float_as_uint(czv[r]);
        stage[slot] = v;
    }
    __syncthreads();

    pairs[(size_t)base + tid]       = stage[tid];
    pairs[(size_t)base + 256 + tid] = stage[256 + tid];
}

// ---------------- K2: XCD-sliced gather ----------------
// block (r = blockIdx%8, j = blockIdx/8) handles buckets r and r+8 in source segments [8j, 8j+8)
__global__ __launch_bounds__(NTHREADS) void k2_gather(
    const float* __restrict__ pos_all,
    const float* __restrict__ vel_all,
    const uint4* __restrict__ pairs,
    const int*   __restrict__ dirs,
    float* __restrict__ partials)
{
    const int r = blockIdx.x & 7;
    const int j = blockIdx.x >> 3;
    const int tid = threadIdx.x;

    __shared__ int dcnt[8][NBUCKET];
    __shared__ int segSrc[8];
    __shared__ int segCum[9];
    __shared__ float wsum[NTHREADS / 64];

    float hsum = 0.f;

    for (int phase = 0; phase < 2; ++phase) {
        const int b = r + 8 * phase;

        if (tid < 8 * NBUCKET) {
            int s = tid >> 4, bb = tid & (NBUCKET - 1);
            dcnt[s][bb] = dirs[(j * 8 + s) * NBUCKET + bb];
        }
        __syncthreads();
        if (tid < 8) {
            int s = tid, st = 0;
            #pragma unroll
            for (int bb = 0; bb < NBUCKET; ++bb) {
                if (bb == b) break;
                st += dcnt[s][bb];
            }
            segSrc[s] = (j * 8 + s) * 512 + st;
            segCum[s] = dcnt[s][b];        // temp: length
        }
        __syncthreads();
        if (tid == 0) {
            int c = 0;
            #pragma unroll
            for (int s = 0; s < 8; ++s) { int l = segCum[s]; segCum[s] = c; c += l; }
            segCum[8] = c;
        }
        __syncthreads();

        const int tot = segCum[8];
        for (int m = tid; m < tot; m += NTHREADS) {
            int s = 0;
            #pragma unroll
            for (int k = 1; k < 8; ++k) s += (m >= segCum[k]);
            uint4 pr = pairs[segSrc[s] + (m - segCum[s])];
            int idx = (int)pr.x;
            const float* pp = pos_all + (size_t)idx * 3;
            const float* vp = vel_all + (size_t)idx * 3;
            float cx = __uint_as_float(pr.y);
            float cy = __uint_as_float(pr.z);
            float cz = __uint_as_float(pr.w);
            hsum += huber3(pp[0] + vp[0] * DT + cx,
                           pp[1] + vp[1] * DT + cy,
                           pp[2] + vp[2] * DT + cz);
        }
        __syncthreads();
    }

    for (int off = 32; off > 0; off >>= 1)
        hsum += __shfl_down(hsum, off);

    int lane = tid & 63, wid = tid >> 6;
    if (lane == 0) wsum[wid] = hsum;
    __syncthreads();
    if (tid == 0) {
        float s = 0.f;
        for (int w = 0; w < NTHREADS / 64; ++w) s += wsum[w];
        partials[blockIdx.x] = s;
    }
}

// ---------------- Fallback: proven round-5 single-pass ----------------
__global__ __launch_bounds__(NTHREADS) void pos_loss_partial(
    const float* __restrict__ quat,
    const float* __restrict__ tpos,
    const float* __restrict__ bias,
    const float* __restrict__ batchX,
    const float* __restrict__ pos_all,
    const float* __restrict__ vel_all,
    const float* __restrict__ grav,
    const int*   __restrict__ indices,
    const int*   __restrict__ seq_len_p,
    int B, int SF,
    float* __restrict__ partials)
{
    const int S = *seq_len_p;
    const int F = SF / S;
    const int last_off = (S - 1) * F;
    const float gx = grav[0], gy = grav[1], gz = grav[2];
    const float half_dt2 = 0.5f * DT * DT;

    float hsum = 0.f;

    for (int i = blockIdx.x * blockDim.x + threadIdx.x; i < B;
         i += gridDim.x * blockDim.x) {
        int idx = ntloadi(indices + i) - (S - 1);
        if (idx < 0) idx = 0;
        const float* pp = pos_all + (size_t)idx * 3;
        const float* vp = vel_all + (size_t)idx * 3;
        float p0x = pp[0], p0y = pp[1], p0z = pp[2];
        float v0x = vp[0], v0y = vp[1], v0z = vp[2];

        float cx, cy, cz;
        stream_compute(quat, tpos, bias, batchX, i, SF, last_off,
                       gx, gy, gz, half_dt2, cx, cy, cz);

        hsum += huber3(p0x + v0x * DT + cx,
                       p0y + v0y * DT + cy,
                       p0z + v0z * DT + cz);
    }

    for (int off = 32; off > 0; off >>= 1)
        hsum += __shfl_down(hsum, off);

    __shared__ float wsum[NTHREADS / 64];
    int lane = threadIdx.x & 63;
    int wid  = threadIdx.x >> 6;
    if (lane == 0) wsum[wid] = hsum;
    __syncthreads();
    if (threadIdx.x == 0) {
        float s = 0.f;
        for (int w = 0; w < NTHREADS / 64; ++w) s += wsum[w];
        partials[blockIdx.x] = s;
    }
}

__global__ __launch_bounds__(NTHREADS) void pos_loss_finish(
    const float* __restrict__ partials, int nb, float inv_cnt,
    float* __restrict__ out)
{
    float s = 0.f;
    for (int i = threadIdx.x; i < nb; i += NTHREADS) s += partials[i];
    for (int off = 32; off > 0; off >>= 1)
        s += __shfl_down(s, off);
    __shared__ float wsum[NTHREADS / 64];
    int lane = threadIdx.x & 63;
    int wid  = threadIdx.x >> 6;
    if (lane == 0) wsum[wid] = s;
    __syncthreads();
    if (threadIdx.x == 0) {
        float tot = 0.f;
        for (int w = 0; w < NTHREADS / 64; ++w) tot += wsum[w];
        out[0] = tot * inv_cnt;
    }
}

extern "C" void kernel_launch(void* const* d_in, const int* in_sizes, int n_in,
                              void* d_out, int out_size, void* d_ws, size_t ws_size,
                              hipStream_t stream) {
    const float* quat    = (const float*)d_in[0];
    const float* tpos    = (const float*)d_in[1];
    const float* bias    = (const float*)d_in[2];
    const float* batchX  = (const float*)d_in[3];
    const float* pos_all = (const float*)d_in[4];
    const float* vel_all = (const float*)d_in[5];
    const float* grav    = (const float*)d_in[6];
    const int*   indices = (const int*)d_in[7];
    const int*   seqlen  = (const int*)d_in[8];

    const int B  = in_sizes[0] / 4;
    const int SF = in_sizes[3] / B;
    const int N  = in_sizes[4] / 3;

    float inv_cnt = (float)(1.0 / (3.0 * (double)B));
    float* outp = (float*)d_out;

    // workspace layout for the pipeline
    const int nseg = B / 512;                               // K1 blocks / source segments
    uint4* pairs   = (uint4*)d_ws;
    int*   dirs    = (int*)((char*)d_ws + (size_t)B * 16);
    float* partials= (float*)((char*)d_ws + (size_t)B * 16 + (size_t)nseg * NBUCKET * 4);
    const size_t need = (size_t)B * 16 + (size_t)nseg * NBUCKET * 4 + (size_t)nseg * 4 + 256;

    const bool pipe_ok = (B % 4096 == 0) && (ws_size >= need) && (N > NBUCKET);

    if (pipe_ok) {
        int shift = 0;
        while (((long long)(N - 1) >> shift) >= NBUCKET) ++shift;

        k1_bin_full<<<nseg, NTHREADS, 0, stream>>>(
            quat, tpos, bias, batchX, grav, indices, seqlen,
            SF, shift, pairs, dirs);
        k2_gather<<<nseg, NTHREADS, 0, stream>>>(
            pos_all, vel_all, pairs, dirs, partials);
        pos_loss_finish<<<1, NTHREADS, 0, stream>>>(
            partials, nseg, inv_cnt, outp);
    } else {
        float* fpart = (float*)d_ws;
        pos_loss_partial<<<NBLOCKS, NTHREADS, 0, stream>>>(
            quat, tpos, bias, batchX, pos_all, vel_all, grav, indices, seqlen,
            B, SF, fpart);
        pos_loss_finish<<<1, NTHREADS, 0, stream>>>(
            fpart, NBLOCKS, inv_cnt, outp);
    }
}

// Round 12
// 59.564 us; speedup vs baseline: 1.2075x; 1.0627x over previous
//
#include <hip/hip_runtime.h>
#include <math.h>

#define DT 0.005f
#define NTHREADS 256
#define NBLOCKS 2048
#define NBUCKET 32
#define ELEMS_PER_BLOCK 1024
#define ROUNDS 4

typedef float    fvec4 __attribute__((ext_vector_type(4)));
typedef float    fvec2 __attribute__((ext_vector_type(2)));
typedef unsigned uvec4 __attribute__((ext_vector_type(4)));

__device__ __forceinline__ fvec4 ntload4f(const float* p) {
    return __builtin_nontemporal_load(reinterpret_cast<const fvec4*>(p));
}
__device__ __forceinline__ fvec2 ntload2f(const float* p) {
    return __builtin_nontemporal_load(reinterpret_cast<const fvec2*>(p));
}
__device__ __forceinline__ float ntloadf(const float* p) {
    return __builtin_nontemporal_load(p);
}
__device__ __forceinline__ int ntloadi(const int* p) {
    return __builtin_nontemporal_load(p);
}
__device__ __forceinline__ uvec4 ntload4u(const unsigned* p) {
    return __builtin_nontemporal_load(reinterpret_cast<const uvec4*>(p));
}

__device__ __forceinline__ void stream_compute(
    const float* __restrict__ quat, const float* __restrict__ tpos,
    const float* __restrict__ bias, const float* __restrict__ batchX,
    int i, int SF, int last_off,
    float gx, float gy, float gz, float half_dt2,
    float& cx, float& cy, float& cz)
{
    fvec4 q = ntload4f(quat + (size_t)i * 4);
    const float* tp = tpos + (size_t)i * 3;
    float tpx = ntloadf(tp + 0), tpy = ntloadf(tp + 1), tpz = ntloadf(tp + 2);
    const float* bp = bias + (size_t)i * 3;
    float bx = ntloadf(bp + 0), by = ntloadf(bp + 1), bz = ntloadf(bp + 2);
    const float* xb = batchX + (size_t)i * SF + last_off;
    fvec2 a01 = ntload2f(xb);          // byte offset 8-aligned (SF even, last_off even)
    float ax = a01.x - bx;
    float ay = a01.y - by;
    float az = ntloadf(xb + 2) - bz;

    float t0 = -(q.y * ax + q.z * ay + q.w * az);
    float t1 =   q.x * ax + q.z * az - q.w * ay;
    float t2 =   q.x * ay - q.y * az + q.w * ax;
    float t3 =   q.x * az + q.y * ay - q.z * ax;
    float rx = -t0 * q.y + t1 * q.x - t2 * q.w + t3 * q.z;
    float ry = -t0 * q.z + t1 * q.w + t2 * q.x - t3 * q.y;
    float rz = -t0 * q.w - t1 * q.z + t2 * q.y + t3 * q.x;

    cx = half_dt2 * (gx + rx) - tpx;
    cy = half_dt2 * (gy + ry) - tpy;
    cz = half_dt2 * (gz + rz) - tpz;
}

__device__ __forceinline__ float huber3(float dx, float dy, float dz) {
    float adx = fabsf(dx), ady = fabsf(dy), adz = fabsf(dz);
    float h = (adx < 1.f) ? 0.5f * dx * dx : adx - 0.5f;
    h += (ady < 1.f) ? 0.5f * dy * dy : ady - 0.5f;
    h += (adz < 1.f) ? 0.5f * dz * dz : adz - 0.5f;
    return h;
}

// ---------------- K1: stream + deterministic 32-bucket multisplit ----------------
__global__ __launch_bounds__(NTHREADS) void k1_bin(
    const float* __restrict__ quat,
    const float* __restrict__ tpos,
    const float* __restrict__ bias,
    const float* __restrict__ batchX,
    const float* __restrict__ grav,
    const int*   __restrict__ indices,
    const int*   __restrict__ seq_len_p,
    int SF, int shift,
    uvec4* __restrict__ pairs,      // B entries, block-contiguous bucket-sorted
    int*   __restrict__ dirs)       // nseg*NBUCKET counts
{
    const int S = *seq_len_p;
    const int F = SF / S;
    const int last_off = (S - 1) * F;
    const float gx = grav[0], gy = grav[1], gz = grav[2];
    const float half_dt2 = 0.5f * DT * DT;

    __shared__ int   cnt[ROUNDS][4][NBUCKET];
    __shared__ int   offarr[ROUNDS][4][NBUCKET];
    __shared__ int   bstart[NBUCKET];
    __shared__ uvec4 stage[ELEMS_PER_BLOCK];

    const int tid  = threadIdx.x;
    const int wave = tid >> 6;
    const int lane = tid & 63;
    const unsigned long long ltmask = (1ull << lane) - 1ull;

    for (int k = tid; k < ROUNDS * 4 * NBUCKET; k += NTHREADS)
        ((int*)cnt)[k] = 0;
    __syncthreads();

    const int base = blockIdx.x * ELEMS_PER_BLOCK;

    int   idxv[ROUNDS], bckt[ROUNDS], rnk[ROUNDS];
    float cxv[ROUNDS], cyv[ROUNDS], czv[ROUNDS];

    #pragma unroll
    for (int r = 0; r < ROUNDS; ++r) {
        const int i = base + r * NTHREADS + tid;
        int idx = ntloadi(indices + i) - (S - 1);
        if (idx < 0) idx = 0;
        idxv[r] = idx;
        int b = idx >> shift; if (b > NBUCKET - 1) b = NBUCKET - 1;
        bckt[r] = b;

        unsigned long long mask = ~0ull;
        #pragma unroll
        for (int k = 0; k < 5; ++k) {
            unsigned long long bm = __ballot((b >> k) & 1);
            mask &= ((b >> k) & 1) ? bm : ~bm;
        }
        rnk[r] = __popcll(mask & ltmask);
        if (rnk[r] == 0) cnt[r][wave][b] = __popcll(mask);

        stream_compute(quat, tpos, bias, batchX, i, SF, last_off,
                       gx, gy, gz, half_dt2, cxv[r], cyv[r], czv[r]);
    }
    __syncthreads();

    // deterministic per-bucket scan over (round, wave) in fixed order
    if (tid < NBUCKET) {
        int b = tid, off = 0;
        #pragma unroll
        for (int r = 0; r < ROUNDS; ++r)
            #pragma unroll
            for (int w = 0; w < 4; ++w) {
                offarr[r][w][b] = off;
                off += cnt[r][w][b];
            }
        dirs[blockIdx.x * NBUCKET + b] = off;
        cnt[0][0][b] = off;   // totals
    }
    __syncthreads();
    if (tid == 0) {
        int s = 0;
        #pragma unroll
        for (int b = 0; b < NBUCKET; ++b) { bstart[b] = s; s += cnt[0][0][b]; }
    }
    __syncthreads();

    #pragma unroll
    for (int r = 0; r < ROUNDS; ++r) {
        int slot = bstart[bckt[r]] + offarr[r][wave][bckt[r]] + rnk[r];
        uvec4 v;
        v.x = (unsigned)idxv[r];
        v.y = __float_as_uint(cxv[r]);
        v.z = __float_as_uint(cyv[r]);
        v.w = __float_as_uint(czv[r]);
        stage[slot] = v;
    }
    __syncthreads();

    #pragma unroll
    for (int r = 0; r < ROUNDS; ++r)
        pairs[(size_t)base + r * NTHREADS + tid] = stage[r * NTHREADS + tid];
}

// ---------------- K2: XCD-sliced gather ----------------
// block (r = blockIdx%8, j = blockIdx/8): phases b = r, r+8, r+16, r+24 over segments [8j, 8j+8)
__global__ __launch_bounds__(NTHREADS) void k2_gather(
    const float* __restrict__ pos_all,
    const float* __restrict__ vel_all,
    const uvec4* __restrict__ pairs,
    const int*   __restrict__ dirs,
    float* __restrict__ partials)
{
    const int r = blockIdx.x & 7;
    const int j = blockIdx.x >> 3;
    const int tid = threadIdx.x;

    __shared__ int dcnt[8][NBUCKET];
    __shared__ int segSrc[8];
    __shared__ int segCum[9];
    __shared__ float wsum[NTHREADS / 64];

    // load the 8 segment directories once (8*32 = 256 = NTHREADS)
    {
        int s = tid >> 5, bb = tid & (NBUCKET - 1);
        dcnt[s][bb] = dirs[(j * 8 + s) * NBUCKET + bb];
    }
    __syncthreads();

    float hsum = 0.f;

    for (int phase = 0; phase < NBUCKET / 8; ++phase) {
        const int b = r + 8 * phase;

        if (tid < 8) {
            int s = tid, st = 0;
            for (int bb = 0; bb < b; ++bb) st += dcnt[s][bb];
            segSrc[s] = (j * 8 + s) * ELEMS_PER_BLOCK + st;
            segCum[s] = dcnt[s][b];        // temp: length
        }
        __syncthreads();
        if (tid == 0) {
            int c = 0;
            #pragma unroll
            for (int s = 0; s < 8; ++s) { int l = segCum[s]; segCum[s] = c; c += l; }
            segCum[8] = c;
        }
        __syncthreads();

        const int tot = segCum[8];
        for (int m = tid; m < tot; m += NTHREADS) {
            int s = 0;
            #pragma unroll
            for (int k = 1; k < 8; ++k) s += (m >= segCum[k]);
            uvec4 pr = ntload4u(
                reinterpret_cast<const unsigned*>(pairs + segSrc[s] + (m - segCum[s])));
            int idx = (int)pr.x;
            const float* pp = pos_all + (size_t)idx * 3;
            const float* vp = vel_all + (size_t)idx * 3;
            float cx = __uint_as_float(pr.y);
            float cy = __uint_as_float(pr.z);
            float cz = __uint_as_float(pr.w);
            hsum += huber3(pp[0] + vp[0] * DT + cx,
                           pp[1] + vp[1] * DT + cy,
                           pp[2] + vp[2] * DT + cz);
        }
        __syncthreads();
    }

    for (int off = 32; off > 0; off >>= 1)
        hsum += __shfl_down(hsum, off);

    int lane = tid & 63, wid = tid >> 6;
    if (lane == 0) wsum[wid] = hsum;
    __syncthreads();
    if (tid == 0) {
        float s = 0.f;
        for (int w = 0; w < NTHREADS / 64; ++w) s += wsum[w];
        partials[blockIdx.x] = s;
    }
}

// ---------------- Fallback: proven round-5 single-pass ----------------
__global__ __launch_bounds__(NTHREADS) void pos_loss_partial(
    const float* __restrict__ quat,
    const float* __restrict__ tpos,
    const float* __restrict__ bias,
    const float* __restrict__ batchX,
    const float* __restrict__ pos_all,
    const float* __restrict__ vel_all,
    const float* __restrict__ grav,
    const int*   __restrict__ indices,
    const int*   __restrict__ seq_len_p,
    int B, int SF,
    float* __restrict__ partials)
{
    const int S = *seq_len_p;
    const int F = SF / S;
    const int last_off = (S - 1) * F;
    const float gx = grav[0], gy = grav[1], gz = grav[2];
    const float half_dt2 = 0.5f * DT * DT;

    float hsum = 0.f;

    for (int i = blockIdx.x * blockDim.x + threadIdx.x; i < B;
         i += gridDim.x * blockDim.x) {
        int idx = ntloadi(indices + i) - (S - 1);
        if (idx < 0) idx = 0;
        const float* pp = pos_all + (size_t)idx * 3;
        const float* vp = vel_all + (size_t)idx * 3;
        float p0x = pp[0], p0y = pp[1], p0z = pp[2];
        float v0x = vp[0], v0y = vp[1], v0z = vp[2];

        float cx, cy, cz;
        stream_compute(quat, tpos, bias, batchX, i, SF, last_off,
                       gx, gy, gz, half_dt2, cx, cy, cz);

        hsum += huber3(p0x + v0x * DT + cx,
                       p0y + v0y * DT + cy,
                       p0z + v0z * DT + cz);
    }

    for (int off = 32; off > 0; off >>= 1)
        hsum += __shfl_down(hsum, off);

    __shared__ float wsum[NTHREADS / 64];
    int lane = threadIdx.x & 63;
    int wid  = threadIdx.x >> 6;
    if (lane == 0) wsum[wid] = hsum;
    __syncthreads();
    if (threadIdx.x == 0) {
        float s = 0.f;
        for (int w = 0; w < NTHREADS / 64; ++w) s += wsum[w];
        partials[blockIdx.x] = s;
    }
}

__global__ __launch_bounds__(NTHREADS) void pos_loss_finish(
    const float* __restrict__ partials, int nb, float inv_cnt,
    float* __restrict__ out)
{
    float s = 0.f;
    for (int i = threadIdx.x; i < nb; i += NTHREADS) s += partials[i];
    for (int off = 32; off > 0; off >>= 1)
        s += __shfl_down(s, off);
    __shared__ float wsum[NTHREADS / 64];
    int lane = threadIdx.x & 63;
    int wid  = threadIdx.x >> 6;
    if (lane == 0) wsum[wid] = s;
    __syncthreads();
    if (threadIdx.x == 0) {
        float tot = 0.f;
        for (int w = 0; w < NTHREADS / 64; ++w) tot += wsum[w];
        out[0] = tot * inv_cnt;
    }
}

extern "C" void kernel_launch(void* const* d_in, const int* in_sizes, int n_in,
                              void* d_out, int out_size, void* d_ws, size_t ws_size,
                              hipStream_t stream) {
    const float* quat    = (const float*)d_in[0];
    const float* tpos    = (const float*)d_in[1];
    const float* bias    = (const float*)d_in[2];
    const float* batchX  = (const float*)d_in[3];
    const float* pos_all = (const float*)d_in[4];
    const float* vel_all = (const float*)d_in[5];
    const float* grav    = (const float*)d_in[6];
    const int*   indices = (const int*)d_in[7];
    const int*   seqlen  = (const int*)d_in[8];

    const int B  = in_sizes[0] / 4;
    const int SF = in_sizes[3] / B;
    const int N  = in_sizes[4] / 3;

    float inv_cnt = (float)(1.0 / (3.0 * (double)B));
    float* outp = (float*)d_out;

    const int nseg = B / ELEMS_PER_BLOCK;          // K1 blocks / source segments
    uvec4* pairs    = (uvec4*)d_ws;
    int*   dirs     = (int*)((char*)d_ws + (size_t)B * 16);
    float* partials = (float*)((char*)d_ws + (size_t)B * 16 +
                               (size_t)nseg * NBUCKET * 4);
    const size_t need = (size_t)B * 16 + (size_t)nseg * NBUCKET * 4 +
                        (size_t)nseg * 4 + 256;

    const bool pipe_ok = (B % (ELEMS_PER_BLOCK * 8) == 0) && (ws_size >= need) &&
                         (N > NBUCKET);

    if (pipe_ok) {
        int shift = 0;
        while (((long long)(N - 1) >> shift) >= NBUCKET) ++shift;

        k1_bin<<<nseg, NTHREADS, 0, stream>>>(
            quat, tpos, bias, batchX, grav, indices, seqlen,
            SF, shift, pairs, dirs);
        k2_gather<<<nseg, NTHREADS, 0, stream>>>(
            pos_all, vel_all, pairs, dirs, partials);
        pos_loss_finish<<<1, NTHREADS, 0, stream>>>(
            partials, nseg, inv_cnt, outp);
    } else {
        float* fpart = (float*)d_ws;
        pos_loss_partial<<<NBLOCKS, NTHREADS, 0, stream>>>(
            quat, tpos, bias, batchX, pos_all, vel_all, grav, indices, seqlen,
            B, SF, fpart);
        pos_loss_finish<<<1, NTHREADS, 0, stream>>>(
            fpart, NBLOCKS, inv_cnt, outp);
    }
}